// Round 7
// baseline (798.783 us; speedup 1.0000x reference)
//
#include <hip/hip_runtime.h>
#include <stdint.h>

// ---------- types ----------
typedef __attribute__((ext_vector_type(8)))  __bf16 bf16x8;   // MFMA A/B frag (4 VGPRs)
typedef __attribute__((ext_vector_type(16))) float  f32x16;   // 32x32 MFMA C/D frag
typedef unsigned short u16;
typedef __attribute__((ext_vector_type(8))) unsigned short u16x8;

#define GLOBAL_AS __attribute__((address_space(1)))
#define LDS_AS    __attribute__((address_space(3)))

__device__ __forceinline__ void load_lds16(const void* g, void* l) {
    __builtin_amdgcn_global_load_lds((const GLOBAL_AS void*)g, (LDS_AS void*)l, 16, 0, 0);
}

__device__ __forceinline__ u16 f2bf(float f) {
    union { float f; uint32_t u; } v; v.f = f;
    uint32_t r = v.u + 0x7FFFu + ((v.u >> 16) & 1u);   // RNE
    return (u16)(r >> 16);
}
__device__ __forceinline__ float b2f(u16 b) {
    union { uint32_t u; float f; } v; v.u = ((uint32_t)b) << 16;
    return v.f;
}

// ---------- aux: fp32 -> bf16 convert with zero-padding ----------
__global__ void k_conv_pad(const float* __restrict__ in, u16* __restrict__ out,
                           int rIn, int cIn, int cOut, int total8) {
    int idx = blockIdx.x * blockDim.x + threadIdx.x;
    if (idx >= total8) return;
    int c8n = cOut >> 3;
    int r  = idx / c8n;
    int c0 = (idx - r * c8n) << 3;
    u16x8 o;
#pragma unroll
    for (int j = 0; j < 8; ++j) {
        int c = c0 + j;
        o[j] = (r < rIn && c < cIn) ? f2bf(in[(size_t)r * cIn + c]) : (u16)0;
    }
    *(u16x8*)(out + (size_t)r * cOut + c0) = o;
}

// ---------- aux: fp32 [kIn x nIn] -> bf16 transposed [nOut x kOut], zero-padded ----------
__global__ void k_transpose_conv(const float* __restrict__ in, u16* __restrict__ out,
                                 int kIn, int nIn, int kOut) {
    __shared__ float tile[32][33];
    int k0 = blockIdx.x * 32, n0 = blockIdx.y * 32;
    int tx = threadIdx.x, ty = threadIdx.y;   // block (32,8)
#pragma unroll
    for (int i = 0; i < 4; ++i) {
        int k = k0 + ty + i * 8, n = n0 + tx;
        tile[ty + i * 8][tx] = (k < kIn && n < nIn) ? in[(size_t)k * nIn + n] : 0.f;
    }
    __syncthreads();
#pragma unroll
    for (int i = 0; i < 4; ++i) {
        int n = n0 + ty + i * 8, k = k0 + tx;
        out[(size_t)n * kOut + k] = f2bf(tile[tx][ty + i * 8]);
    }
}

// ---------- main GEMM: C[M,N] = A[M,K] @ B[N,K]^T  (both bf16, K contiguous) ----------
// MODE 0: store bf16 with (row<mReal && col<nReal) guard (ldc = nReal)
// MODE 1: bf16 out = relu(acc + bias[col])
// MODE 2: fp32 out = acc + bias[col]
// 128x128 tile, BK=64, 4 waves each 64x64 as 2x2 of 32x32x16 MFMA.
// DEPTH-2 PIPELINED K-LOOP (R6 model: per-iter __syncthreads vmcnt(0) drain was
// ~50% of slot time; compute:staging = 1:6 at this K):
//   prologue stages tiles 0,1 into 2x32KB LDS buffers;
//   iter i: s_waitcnt vmcnt(8) (own tile-i DMAs done, tile i+1 stays in flight;
//           per-wave FIFO semantics m135) + raw s_barrier -> compute ->
//           raw s_barrier (no drain: every ds_read was consumed by an MFMA,
//           so lgkm waits already retired them) -> issue tile i+2 DMA.
//   sched_barrier(0) pins the machine scheduler at both handoffs.
// LDS 64KB -> 2 blocks/CU; launch_bounds(256,2) relaxes the reg cap.
// Swizzle c^(r&7) kept (residual +4cyc/b128 proven swizzle-invariant R3/R4).
// Supertile remap GM=8 kept (harmless, helps fetch at lower residency).
template <int MODE>
__global__ __launch_bounds__(256, 2) void k_gemm_bt(
    const u16* __restrict__ A, const u16* __restrict__ B,
    const u16* __restrict__ bias, void* __restrict__ Cv,
    int K, int ldc, int mReal, int nReal) {
    (void)bias;
    __shared__ __align__(16) char lds[65536];   // As0|Bs0|As1|Bs1, 16KB each

    const int tid  = threadIdx.x;
    const int w    = tid >> 6, lane = tid & 63;
    const int l31  = lane & 31, hi = lane >> 5;
    const int wm   = (w & 1) * 64, wn = (w >> 1) * 64;

    // supertile remap: id -> (tm, tn); GM M-tiles per super, column-major inside
    const int id     = blockIdx.y * gridDim.x + blockIdx.x;
    const int gridM  = gridDim.y, gridN = gridDim.x;
    const int GM     = 8;
    const int perSup = GM * gridN;
    const int super  = id / perSup;
    const int rem    = id - super * perSup;
    const int sm0    = super * GM;
    const int smH    = (gridM - sm0 < GM) ? (gridM - sm0) : GM;
    const int tm     = sm0 + rem % smH;
    const int tn     = rem / smH;
    const int bm = tm * 128, bn = tn * 128;

    // staging: thread tid fetches global (row = tid>>3 + 32t, chunk = (tid&7)^(row&7))
    const int srcRow = tid >> 3;
    const int srcCol = (tid & 7) ^ (srcRow & 7);
    const u16* aSrc = A + (size_t)(bm + srcRow) * K + (srcCol << 3);
    const u16* bSrc = B + (size_t)(bn + srcRow) * K + (srcCol << 3);
    const int ldsOff = (tid & ~63) << 4;   // wave-uniform chunk base within buffer

    const int nIter = K >> 6;

    // stage tile j (K-offset j*64) into LDS buffer j&1: 8 DMA instrs per wave
    auto stage = [&](int j) {
        char* aD = lds + ((j & 1) << 15) + ldsOff;
        char* bD = aD + 16384;
        const u16* aS = aSrc + (j << 6);
        const u16* bS = bSrc + (j << 6);
#pragma unroll
        for (int t = 0; t < 4; ++t) {
            load_lds16(aS + (size_t)(t * 32) * K, aD + t * 4096);
            load_lds16(bS + (size_t)(t * 32) * K, bD + t * 4096);
        }
    };

    // precomputed LDS row byte-offsets within a buffer (swz added per ks)
    const int aRow0 = (wm + l31) * 128;
    const int aRow1 = (wm + 32 + l31) * 128;
    const int bRow0 = (wn + l31) * 128;
    const int bRow1 = (wn + 32 + l31) * 128;

    f32x16 acc[2][2];
#pragma unroll
    for (int i = 0; i < 2; ++i)
#pragma unroll
        for (int j = 0; j < 2; ++j) acc[i][j] = (f32x16)(0.f);

    stage(0);
    stage(1);

    for (int i = 0; i < nIter; ++i) {
        // wait own tile-i DMAs (8 in flight beyond them while i<nIter-1)
        if (i < nIter - 1) __builtin_amdgcn_s_waitcnt(0xF78);  // vmcnt(8)
        else               __builtin_amdgcn_s_waitcnt(0xF70);  // vmcnt(0)
        __builtin_amdgcn_s_barrier();
        __builtin_amdgcn_sched_barrier(0);

        const char* Ac = lds + ((i & 1) << 15);
        const char* Bc = Ac + 16384;
#pragma unroll
        for (int ks = 0; ks < 4; ++ks) {
            const int swz = (((ks * 2 + hi) ^ (l31 & 7)) << 4);
            bf16x8 af[2], bfr[2];
            af[0]  = *(const bf16x8*)(Ac + aRow0 + swz);
            af[1]  = *(const bf16x8*)(Ac + aRow1 + swz);
            bfr[0] = *(const bf16x8*)(Bc + bRow0 + swz);
            bfr[1] = *(const bf16x8*)(Bc + bRow1 + swz);
#pragma unroll
            for (int mi = 0; mi < 2; ++mi)
#pragma unroll
                for (int ni = 0; ni < 2; ++ni)
                    acc[mi][ni] = __builtin_amdgcn_mfma_f32_32x32x16_bf16(
                        af[mi], bfr[ni], acc[mi][ni], 0, 0, 0);
        }

        __builtin_amdgcn_sched_barrier(0);
        __builtin_amdgcn_s_barrier();     // all waves done reading buf[i&1]
        if (i + 2 < nIter) stage(i + 2);  // refill the freed buffer
    }

    // epilogue. 32x32 C/D layout: col = lane&31, row = (reg&3) + 8*(reg>>2) + 4*hi
    // (m74/m101-verified)
    float bv[2];
    if (MODE >= 1) {
#pragma unroll
        for (int ni = 0; ni < 2; ++ni) bv[ni] = b2f(bias[bn + wn + ni * 32 + l31]);
    }
#pragma unroll
    for (int mi = 0; mi < 2; ++mi) {
#pragma unroll
        for (int reg = 0; reg < 16; ++reg) {
            int row = bm + wm + mi * 32 + (reg & 3) + 8 * (reg >> 2) + 4 * hi;
#pragma unroll
            for (int ni = 0; ni < 2; ++ni) {
                int col = bn + wn + ni * 32 + l31;
                float v = acc[mi][ni][reg];
                if (MODE == 0) {
                    if (row < mReal && col < nReal)
                        ((u16*)Cv)[(size_t)row * ldc + col] = f2bf(v);
                } else if (MODE == 1) {
                    v += bv[ni];
                    v = v > 0.f ? v : 0.f;
                    ((u16*)Cv)[(size_t)row * ldc + col] = f2bf(v);
                } else {
                    ((float*)Cv)[(size_t)row * ldc + col] = v + bv[ni];
                }
            }
        }
    }
}

// ---------- launch ----------
// Sizes: D_IN=2048, D_H=4096, D_OUT=2048, B=4096; SIZE_N=5794, SIZE_M=2897
// Padded GEMM0 dims: M=N=5888 (46*128), K=2944 (46*64)
// Vf flat unpack offsets (elems):
//   W1 @ 0, b1 @ 8388608, W2 @ 8392704, b2 @ 25169920, W3 @ 25174016, b3 @ 33562624
extern "C" void kernel_launch(void* const* d_in, const int* in_sizes, int n_in,
                              void* d_out, int out_size, void* d_ws, size_t ws_size,
                              hipStream_t stream) {
    (void)in_sizes; (void)n_in; (void)out_size; (void)ws_size;
    const float* x  = (const float*)d_in[0];
    const float* V1 = (const float*)d_in[1];
    const float* V2 = (const float*)d_in[2];

    char* ws = (char*)d_ws;
    u16* Vf   = (u16*)(ws);                            // 5794*5794 bf16 -> 67,140,872 B
    u16* V1b  = (u16*)(ws + 67141120);                 // [5888 x 2944] bf16 = 34,668,544 B
    u16* V2bT = (u16*)(ws + 67141120 + 34668544);      // [5888 x 2944] bf16
    u16* Xb   = (u16*)(ws + 67141120 + 2 * 34668544);  // [4096 x 2048] bf16
    u16* H1   = V1b;   // dead after GEMM0
    u16* H2   = V2bT;

    k_conv_pad<<<8464, 256, 0, stream>>>(V1, V1b, 5794, 2897, 2944, 5888 * 2944 / 8);
    k_transpose_conv<<<dim3(92, 184), dim3(32, 8), 0, stream>>>(V2, V2bT, 2897, 5794, 2944);
    k_conv_pad<<<4096, 256, 0, stream>>>(x, Xb, 4096, 2048, 2048, 4096 * 2048 / 8);

    // G0: Vf = V1 @ V2  (padded 5888x5888x2944, guarded store into flat [5794x5794])
    k_gemm_bt<0><<<dim3(46, 46), 256, 0, stream>>>(V1b, V2bT, nullptr, Vf,
                                                   2944, 5794, 5794, 5794);
    // G1: H1 = relu(Xb @ W1^T + b1)   [4096x4096], K=2048
    k_gemm_bt<1><<<dim3(32, 32), 256, 0, stream>>>(Xb, Vf + 0, Vf + 8388608, H1,
                                                   2048, 4096, 4096, 4096);
    // G2: H2 = relu(H1 @ W2^T + b2)   [4096x4096], K=4096
    k_gemm_bt<1><<<dim3(32, 32), 256, 0, stream>>>(H1, Vf + 8392704, Vf + 25169920, H2,
                                                   4096, 4096, 4096, 4096);
    // G3: out = H2 @ W3^T + b3        [4096x2048] fp32, K=4096
    k_gemm_bt<2><<<dim3(16, 32), 256, 0, stream>>>(H2, Vf + 25174016, Vf + 33562624, d_out,
                                                   4096, 2048, 4096, 2048);
}